// Round 13
// baseline (166.628 us; speedup 1.0000x reference)
//
#include <hip/hip_runtime.h>
#include <stdint.h>

#define NBOX 4096
#define IMG 640.0f

typedef unsigned long long u64;
typedef unsigned int u32;

// ws layout (bytes):
//   [0      .. 16384)    sx1   (4096 f32, sorted)
//   [16384  .. 32768)    sy1
//   [32768  .. 49152)    sx2
//   [49152  .. 65536)    sy2
//   [65536  .. 81920)    sconf
//   [81920  .. 81924)    M (int, zeroed by k_rank blk(0,0); k_scatter accumulates)
//   [86016  .. 118784)   diagR  (4096 u64): row r's suppression word within its own diag block
//   [118784 .. 151552)   carry1 (4096 u64): row r's suppression word blk(r)+1
//   [151552 .. 184320)   carry2 (4096 u64): row r's suppression word blk(r)+2
//   [196608 .. 2293760)  mask (ROW-major: mask[row][word], 4096 x 64 u64 = 2 MB)
//   [2293760 .. 2555904) rank_partial (16 x 4096 int = 256 KB)

__global__ __launch_bounds__(256) void k_rank(const float* __restrict__ raw,
                                              int* __restrict__ rank_partial, int* __restrict__ Mp) {
    const int bi = blockIdx.x, bj = blockIdx.y;
    const int t = threadIdx.x;
    const int i = bi * 256 + t;
    if (bi == 0 && bj == 0 && t == 0) *Mp = 0;
    __shared__ float cj[256];
    cj[t] = raw[(bj * 256 + t) * 5 + 4];
    __syncthreads();

    const float ci = raw[i * 5 + 4];
    const int jbase = bj * 256;
    int rank = 0;
    const float4* c4 = reinterpret_cast<const float4*>(cj);
#pragma unroll 4
    for (int j4 = 0; j4 < 64; ++j4) {
        float4 c = c4[j4];
        int j = jbase + j4 * 4;
        rank += (c.x > ci || (c.x == ci && (j + 0) < i)) ? 1 : 0;
        rank += (c.y > ci || (c.y == ci && (j + 1) < i)) ? 1 : 0;
        rank += (c.z > ci || (c.z == ci && (j + 2) < i)) ? 1 : 0;
        rank += (c.w > ci || (c.w == ci && (j + 3) < i)) ? 1 : 0;
    }
    rank_partial[bj * NBOX + i] = rank;
}

__global__ __launch_bounds__(256) void k_scatter(const float* __restrict__ raw,
                                                 const int* __restrict__ rank_partial,
                                                 float* __restrict__ sx1, float* __restrict__ sy1,
                                                 float* __restrict__ sx2, float* __restrict__ sy2,
                                                 float* __restrict__ sconf, int* __restrict__ Mp) {
    const int i = blockIdx.x * 256 + threadIdx.x;
    const float ci = raw[i * 5 + 4];
    const bool vi = (ci >= 0.5f);

    int rank = 0;
#pragma unroll
    for (int k = 0; k < 16; ++k) rank += rank_partial[k * NBOX + i];

    u64 bal = __ballot(vi);
    if ((threadIdx.x & 63) == 0) atomicAdd(Mp, (int)__popcll(bal));

    if (vi) {
        // Strict IEEE ops (no FMA contraction) to match the numpy-evaluated reference.
        float cx = __fmul_rn(raw[i * 5 + 0], IMG);
        float cy = __fmul_rn(raw[i * 5 + 1], IMG);
        float w  = __fmul_rn(raw[i * 5 + 2], IMG);
        float h  = __fmul_rn(raw[i * 5 + 3], IMG);
        float hw = __fmul_rn(w, 0.5f);
        float hh = __fmul_rn(h, 0.5f);
        sx1[rank]   = __fsub_rn(cx, hw);
        sy1[rank]   = __fsub_rn(cy, hh);
        sx2[rank]   = __fadd_rn(cx, hw);
        sy2[rank]   = __fadd_rn(cy, hh);
        sconf[rank] = ci;
    }
}

// Block (bx, w): rows r = bx*256+tid, word w of columns. Row-major mask write;
// also extracts diag word and the two carry columns as contiguous arrays.
__global__ __launch_bounds__(256) void k_mask(const float* __restrict__ sx1, const float* __restrict__ sy1,
                                              const float* __restrict__ sx2, const float* __restrict__ sy2,
                                              const int* __restrict__ Mp,
                                              u64* __restrict__ mask, u64* __restrict__ diagR,
                                              u64* __restrict__ carry1, u64* __restrict__ carry2) {
    const int w = blockIdx.y;                      // column word 0..63
    const int r = blockIdx.x * 256 + threadIdx.x;  // row 0..4095
    const int t = threadIdx.x;
    const int M = *Mp;

    __shared__ float cx1[64], cy1[64], cx2[64], cy2[64], car[64];
    if (t < 64) {
        int j = (w << 6) + t;
        float a1 = sx1[j], b1 = sy1[j], a2 = sx2[j], b2 = sy2[j];
        cx1[t] = a1; cy1[t] = b1; cx2[t] = a2; cy2[t] = b2;
        car[t] = __fmul_rn(__fsub_rn(a2, a1), __fsub_rn(b2, b1));
    }
    __syncthreads();

    u64 bits = 0ULL;
    if (r < M) {
        const float x1 = sx1[r], y1 = sy1[r], x2 = sx2[r], y2 = sy2[r];
        const float area_i = __fmul_rn(__fsub_rn(x2, x1), __fsub_rn(y2, y1));
        const int bmax = min(64, M - (w << 6));       // j < M
        const int bmin = max(0, r + 1 - (w << 6));    // j > r
        for (int b = bmin; b < bmax; ++b) {
            float xx1 = fmaxf(x1, cx1[b]);
            float yy1 = fmaxf(y1, cy1[b]);
            float xx2 = fminf(x2, cx2[b]);
            float yy2 = fminf(y2, cy2[b]);
            float iw = fmaxf(__fsub_rn(xx2, xx1), 0.0f);
            float ih = fmaxf(__fsub_rn(yy2, yy1), 0.0f);
            float inter = __fmul_rn(iw, ih);
            float uni = __fsub_rn(__fadd_rn(area_i, car[b]), inter);
            float iou = __fdiv_rn(inter, fmaxf(uni, 1e-9f));
            if (iou > 0.5f) bits |= (1ULL << b);
        }
        mask[((size_t)r << 6) + w] = bits;            // row-major
    }

    const int rblk = r >> 6;
    if (rblk == w)     diagR[r]  = bits;   // own-word suppression (0 for r >= M)
    if (rblk + 1 == w) carry1[r] = bits;   // word blk+1
    if (rblk + 2 == w) carry2[r] = bits;   // word blk+2
}

// SINGLE-WAVE greedy scan, fully software-pipelined, NO gathers, NO barriers:
//  - diag/carry columns: contiguous 512B loads issued 3 blocks ahead
//  - kept-row folds: issued at block b, folded at b+3 (3-buffer static ring);
//    resolve correctness bridged by carry1 (b-1) + carry2 (b-2), accumulated
//    off-chain in the resolve readlane loop
// NOTE: __builtin_amdgcn_readlane returns *int* -- ALWAYS truncate to u32
// before widening to u64 ((u64)(int) sign-extends: R6/R10 bug).
__global__ __launch_bounds__(256) void k_scan(const int* __restrict__ Mp,
                                              const u64* __restrict__ mask,
                                              const u64* __restrict__ diagR,
                                              const u64* __restrict__ carry1,
                                              const u64* __restrict__ carry2,
                                              const float* __restrict__ sx1, const float* __restrict__ sy1,
                                              const float* __restrict__ sx2, const float* __restrict__ sy2,
                                              const float* __restrict__ sconf,
                                              float* __restrict__ out) {
    __shared__ u64 kbArr[64];
    const int tid = threadIdx.x;
    const int lane = tid & 63;
    const int M = *Mp;
    const int nblk = (M + 63) >> 6;

    if (tid < 64) kbArr[tid] = 0ULL;

    if ((tid >> 6) == 0 && nblk > 0) {
        __builtin_amdgcn_s_setprio(1);
        // depth-3 prefetch pipeline (all contiguous 512B loads)
        u64 d_cur = diagR[lane], c1_cur = carry1[lane], c2_cur = carry2[lane];
        u64 d_n1 = 0, c1_n1 = 0, c2_n1 = 0, d_n2 = 0, c1_n2 = 0, c2_n2 = 0;
        if (1 < nblk) { d_n1 = diagR[64 + lane];  c1_n1 = carry1[64 + lane];  c2_n1 = carry2[64 + lane]; }
        if (2 < nblk) { d_n2 = diagR[128 + lane]; c1_n2 = carry1[128 + lane]; c2_n2 = carry2[128 + lane]; }

        u32 rvlo = 0, rvhi = 0;            // distributed remv word `lane` (folded blocks)
        u64 cA = 0ULL, cB = 0ULL, q2 = 0ULL;  // carries: b-1, b-2, pending car2
        u64 ovA[16], ovB[16], ovC[16];     // lag-3 kept-row loads (static indices only)
        int cntA = 0, cntB = 0, cntC = 0;
        u64 ofA = 0ULL, ofB = 0ULL, ofC = 0ULL;

#define STEP(BIDX, OV, CNT, OFL)                                              \
  do {                                                                        \
    const int b_ = (BIDX);                                                    \
    if (b_ < nblk) {                                                          \
      /* fold block b_-3 (loads issued 3 iters ago; vmcnt has ~3T slack) */   \
      u64 facc = 0ULL;                                                        \
      _Pragma("unroll")                                                       \
      for (int k = 0; k < 16; ++k) facc |= (k < (CNT)) ? (OV)[k] : 0ULL;      \
      if (__builtin_expect((OFL) != 0ULL, 0)) {                               \
        u64 tt = (OFL);                                                       \
        const u64* rb3 = mask + ((size_t)((b_ - 3) << 6) << 6);               \
        while (tt) { int ii = __builtin_ctzll(tt); tt &= tt - 1;              \
                     facc |= rb3[((size_t)ii << 6) + lane]; }                 \
      }                                                                       \
      rvlo |= (u32)facc; rvhi |= (u32)(facc >> 32);                           \
      /* resolve block b_ */                                                  \
      u32 rbl = (u32)__builtin_amdgcn_readlane(rvlo, b_);                     \
      u32 rbh = (u32)__builtin_amdgcn_readlane(rvhi, b_);                     \
      const u64 rb = (((u64)rbh << 32) | (u64)rbl) | cA | cB;                 \
      const int rem = M - (b_ << 6);                                          \
      const u64 valid = (rem >= 64) ? ~0ULL : ((1ULL << rem) - 1ULL);         \
      u64 alive = valid & ~rb;                                                \
      u64 kb = 0ULL, car1 = 0ULL, car2 = 0ULL;                                \
      const u32 dlo = (u32)d_cur, dhi = (u32)(d_cur >> 32);                   \
      const u32 e1l = (u32)c1_cur, e1h = (u32)(c1_cur >> 32);                 \
      const u32 e2l = (u32)c2_cur, e2h = (u32)(c2_cur >> 32);                 \
      while (alive) {                                                         \
        int i = __builtin_ctzll(alive); alive &= alive - 1;                   \
        kb |= (1ULL << i);                                                    \
        u32 lo = (u32)__builtin_amdgcn_readlane(dlo, i);                      \
        u32 hi = (u32)__builtin_amdgcn_readlane(dhi, i);                      \
        u32 p1 = (u32)__builtin_amdgcn_readlane(e1l, i);                      \
        u32 g1 = (u32)__builtin_amdgcn_readlane(e1h, i);                      \
        u32 p2 = (u32)__builtin_amdgcn_readlane(e2l, i);                      \
        u32 g2 = (u32)__builtin_amdgcn_readlane(e2h, i);                      \
        alive &= ~(((u64)hi << 32) | (u64)lo);   /* on-chain */               \
        car1 |= ((u64)g1 << 32) | (u64)p1;       /* off-chain */              \
        car2 |= ((u64)g2 << 32) | (u64)p2;                                    \
      }                                                                       \
      if (lane == 0) kbArr[b_] = kb;                                          \
      cA = car1; cB = q2; q2 = car2;                                          \
      /* issue kept-row loads (fold at b_+3) */                               \
      {                                                                       \
        u64 tt = kb; int cnt = 0;                                             \
        const u64* rowb = mask + ((size_t)(b_ << 6) << 6);                    \
        _Pragma("unroll")                                                     \
        for (int k = 0; k < 16; ++k) {                                        \
          const bool has = (tt != 0ULL);                                      \
          const int ik = has ? __builtin_ctzll(tt) : 0;                       \
          if (has) tt &= tt - 1;                                              \
          cnt += has ? 1 : 0;                                                 \
          (OV)[k] = rowb[((size_t)ik << 6) + lane];   /* 512B coalesced */    \
        }                                                                     \
        (CNT) = cnt; (OFL) = tt;                                              \
      }                                                                       \
      /* rotate depth-3 prefetch */                                           \
      d_cur = d_n1;  d_n1 = d_n2;                                             \
      c1_cur = c1_n1; c1_n1 = c1_n2;                                          \
      c2_cur = c2_n1; c2_n1 = c2_n2;                                          \
      if (b_ + 3 < nblk) {                                                    \
        d_n2  = diagR [((b_ + 3) << 6) + lane];                               \
        c1_n2 = carry1[((b_ + 3) << 6) + lane];                               \
        c2_n2 = carry2[((b_ + 3) << 6) + lane];                               \
      } else { d_n2 = 0ULL; c1_n2 = 0ULL; c2_n2 = 0ULL; }                     \
    }                                                                         \
  } while (0)

        for (int bb = 0; bb < nblk; bb += 3) {
            STEP(bb + 0, ovA, cntA, ofA);
            STEP(bb + 1, ovB, cntB, ofB);
            STEP(bb + 2, ovC, cntC, ofC);
        }
#undef STEP
    }
    __syncthreads();

    // ---- fused output epilogue ----
    for (int g = tid; g < NBOX * 5; g += 256) {
        const int r = g / 5;
        const int c = g - r * 5;
        bool kept = false;
        if (r < M) kept = ((kbArr[r >> 6] >> (r & 63)) & 1ULL) != 0ULL;
        float vv = 0.0f;
        if (kept) {
            const float* arr = (c == 0) ? sx1 : (c == 1) ? sy1 : (c == 2) ? sx2 : (c == 3) ? sy2 : sconf;
            vv = arr[r];
        }
        out[g] = vv;
    }
}

extern "C" void kernel_launch(void* const* d_in, const int* in_sizes, int n_in,
                              void* d_out, int out_size, void* d_ws, size_t ws_size,
                              hipStream_t stream) {
    const float* raw = (const float*)d_in[0];
    char* ws = (char*)d_ws;
    float* sx1 = (float*)(ws + 0);
    float* sy1 = (float*)(ws + 16384);
    float* sx2 = (float*)(ws + 32768);
    float* sy2 = (float*)(ws + 49152);
    float* sconf = (float*)(ws + 65536);
    int* Mp = (int*)(ws + 81920);
    u64* diagR  = (u64*)(ws + 86016);
    u64* carry1 = (u64*)(ws + 118784);
    u64* carry2 = (u64*)(ws + 151552);
    u64* mask = (u64*)(ws + 196608);
    int* rank_partial = (int*)(ws + 2293760);
    float* out = (float*)d_out;

    k_rank<<<dim3(16, 16), dim3(256), 0, stream>>>(raw, rank_partial, Mp);
    k_scatter<<<dim3(16), dim3(256), 0, stream>>>(raw, rank_partial, sx1, sy1, sx2, sy2, sconf, Mp);
    k_mask<<<dim3(16, 64), dim3(256), 0, stream>>>(sx1, sy1, sx2, sy2, Mp, mask, diagR, carry1, carry2);
    k_scan<<<dim3(1), dim3(256), 0, stream>>>(Mp, mask, diagR, carry1, carry2, sx1, sy1, sx2, sy2, sconf, out);
}

// Round 14
// 90.334 us; speedup vs baseline: 1.8446x; 1.8446x over previous
//
#include <hip/hip_runtime.h>
#include <stdint.h>

#define NBOX 4096
#define IMG 640.0f

typedef unsigned long long u64;
typedef unsigned int u32;

// ws layout (bytes):
//   [0      .. 16384)    sx1   (4096 f32, sorted)
//   [16384  .. 32768)    sy1
//   [32768  .. 49152)    sx2
//   [49152  .. 65536)    sy2
//   [65536  .. 81920)    sconf
//   [81920  .. 81924)    M (int)
//   [86016  .. 118784)   diagR  (4096 u64): row r's suppression word blk(r)
//   [118784 .. 151552)   carry1 (4096 u64): row r's suppression word blk(r)+1
//   [196608 .. 2293760)  maskT (COLUMN-major: maskT[word][row], 64 x 4096 u64 = 2 MB)
//   [2293760 .. 2555904) rank_partial (16 x 4096 int = 256 KB)

__global__ __launch_bounds__(256) void k_rank(const float* __restrict__ raw,
                                              int* __restrict__ rank_partial, int* __restrict__ Mp) {
    const int bi = blockIdx.x, bj = blockIdx.y;
    const int t = threadIdx.x;
    const int i = bi * 256 + t;
    if (bi == 0 && bj == 0 && t == 0) *Mp = 0;
    __shared__ float cj[256];
    cj[t] = raw[(bj * 256 + t) * 5 + 4];
    __syncthreads();

    const float ci = raw[i * 5 + 4];
    const int jbase = bj * 256;
    int rank = 0;
    const float4* c4 = reinterpret_cast<const float4*>(cj);
#pragma unroll 4
    for (int j4 = 0; j4 < 64; ++j4) {
        float4 c = c4[j4];
        int j = jbase + j4 * 4;
        rank += (c.x > ci || (c.x == ci && (j + 0) < i)) ? 1 : 0;
        rank += (c.y > ci || (c.y == ci && (j + 1) < i)) ? 1 : 0;
        rank += (c.z > ci || (c.z == ci && (j + 2) < i)) ? 1 : 0;
        rank += (c.w > ci || (c.w == ci && (j + 3) < i)) ? 1 : 0;
    }
    rank_partial[bj * NBOX + i] = rank;
}

__global__ __launch_bounds__(256) void k_scatter(const float* __restrict__ raw,
                                                 const int* __restrict__ rank_partial,
                                                 float* __restrict__ sx1, float* __restrict__ sy1,
                                                 float* __restrict__ sx2, float* __restrict__ sy2,
                                                 float* __restrict__ sconf, int* __restrict__ Mp) {
    const int i = blockIdx.x * 256 + threadIdx.x;
    const float ci = raw[i * 5 + 4];
    const bool vi = (ci >= 0.5f);

    int rank = 0;
#pragma unroll
    for (int k = 0; k < 16; ++k) rank += rank_partial[k * NBOX + i];

    u64 bal = __ballot(vi);
    if ((threadIdx.x & 63) == 0) atomicAdd(Mp, (int)__popcll(bal));

    if (vi) {
        // Strict IEEE ops (no FMA contraction) to match the numpy-evaluated reference.
        float cx = __fmul_rn(raw[i * 5 + 0], IMG);
        float cy = __fmul_rn(raw[i * 5 + 1], IMG);
        float w  = __fmul_rn(raw[i * 5 + 2], IMG);
        float h  = __fmul_rn(raw[i * 5 + 3], IMG);
        float hw = __fmul_rn(w, 0.5f);
        float hh = __fmul_rn(h, 0.5f);
        sx1[rank]   = __fsub_rn(cx, hw);
        sy1[rank]   = __fsub_rn(cy, hh);
        sx2[rank]   = __fadd_rn(cx, hw);
        sy2[rank]   = __fadd_rn(cy, hh);
        sconf[rank] = ci;
    }
}

// Block (bx, w): rows r = bx*256+tid, word w. Column-major store (coalesced);
// also extracts diag word + carry1 column as contiguous arrays.
__global__ __launch_bounds__(256) void k_mask(const float* __restrict__ sx1, const float* __restrict__ sy1,
                                              const float* __restrict__ sx2, const float* __restrict__ sy2,
                                              const int* __restrict__ Mp,
                                              u64* __restrict__ maskT, u64* __restrict__ diagR,
                                              u64* __restrict__ carry1) {
    const int w = blockIdx.y;
    const int r = blockIdx.x * 256 + threadIdx.x;
    const int t = threadIdx.x;
    const int M = *Mp;

    __shared__ float cx1[64], cy1[64], cx2[64], cy2[64], car[64];
    if (t < 64) {
        int j = (w << 6) + t;
        float a1 = sx1[j], b1 = sy1[j], a2 = sx2[j], b2 = sy2[j];
        cx1[t] = a1; cy1[t] = b1; cx2[t] = a2; cy2[t] = b2;
        car[t] = __fmul_rn(__fsub_rn(a2, a1), __fsub_rn(b2, b1));
    }
    __syncthreads();

    u64 bits = 0ULL;
    if (r < M) {
        const float x1 = sx1[r], y1 = sy1[r], x2 = sx2[r], y2 = sy2[r];
        const float area_i = __fmul_rn(__fsub_rn(x2, x1), __fsub_rn(y2, y1));
        const int bmax = min(64, M - (w << 6));       // j < M
        const int bmin = max(0, r + 1 - (w << 6));    // j > r
        for (int b = bmin; b < bmax; ++b) {
            float xx1 = fmaxf(x1, cx1[b]);
            float yy1 = fmaxf(y1, cy1[b]);
            float xx2 = fminf(x2, cx2[b]);
            float yy2 = fminf(y2, cy2[b]);
            float iw = fmaxf(__fsub_rn(xx2, xx1), 0.0f);
            float ih = fmaxf(__fsub_rn(yy2, yy1), 0.0f);
            float inter = __fmul_rn(iw, ih);
            float uni = __fsub_rn(__fadd_rn(area_i, car[b]), inter);
            float iou = __fdiv_rn(inter, fmaxf(uni, 1e-9f));
            if (iou > 0.5f) bits |= (1ULL << b);
        }
        maskT[((size_t)w << 12) + r] = bits;          // coalesced column-major
    }

    const int rblk = r >> 6;
    if (rblk == w)     diagR[r]  = bits;
    if (rblk + 1 == w) carry1[r] = bits;
}

// 9 waves, 1 KiB LDS, 1 barrier/block. ALL memory traffic is b-indexed streams
// (no scan-dependent addresses anywhere):
//  wave 0 : resolve block b from depth-3-streamed diagR/carry1; carry to word
//           b+1 accumulated in-resolve (R12 logic, carry2 dropped -- bg covers it).
//  waves 1-8: fold block b-1 into remvArr[b+1..63] from a depth-2 column ring
//           (ALL 64 rows loaded unconditionally, kb applied as a register mask).
// NOTE: __builtin_amdgcn_readlane returns *int* -- truncate to u32 before
// widening ((u64)(int) sign-extends: R6/R10 bug).
__global__ __launch_bounds__(576) void k_scan(const int* __restrict__ Mp,
                                              const u64* __restrict__ maskT,
                                              const u64* __restrict__ diagR,
                                              const u64* __restrict__ carry1,
                                              const float* __restrict__ sx1, const float* __restrict__ sy1,
                                              const float* __restrict__ sx2, const float* __restrict__ sy2,
                                              const float* __restrict__ sconf,
                                              float* __restrict__ out) {
    __shared__ u64 remvArr[64];
    __shared__ u64 kbArr[64];
    const int tid = threadIdx.x;
    const int wave = tid >> 6;
    const int lane = tid & 63;
    const int M = *Mp;
    const int nblk = (M + 63) >> 6;

    if (tid < 64) { remvArr[tid] = 0ULL; kbArr[tid] = 0ULL; }
    __syncthreads();

    if (nblk > 0) {
        if (wave == 0) {
            __builtin_amdgcn_s_setprio(1);
            // depth-3 streams (contiguous 512B loads, b-indexed only)
            u64 d0 = diagR[lane], e0 = carry1[lane];
            u64 d1 = 0, e1 = 0, d2 = 0, e2 = 0;
            if (1 < nblk) { d1 = diagR[64 + lane];  e1 = carry1[64 + lane];  }
            if (2 < nblk) { d2 = diagR[128 + lane]; e2 = carry1[128 + lane]; }
            u64 carry = 0ULL;                       // block b-1 kept -> word b

            for (int b = 0; b < nblk; ++b) {
                const u64 rb = remvArr[b] | carry;  // blocks <= b-2 via bg; b-1 via carry
                const int rem = M - (b << 6);
                const u64 valid = (rem >= 64) ? ~0ULL : ((1ULL << rem) - 1ULL);
                u64 alive = valid & ~rb;
                u64 kb = 0ULL, car = 0ULL;
                const u32 dlo = (u32)d0, dhi = (u32)(d0 >> 32);
                const u32 el = (u32)e0, eh = (u32)(e0 >> 32);
                while (alive) {                     // uniform; kept boxes only
                    int i = __builtin_ctzll(alive);
                    alive &= alive - 1;
                    kb |= (1ULL << i);
                    u32 lo = (u32)__builtin_amdgcn_readlane(dlo, i);
                    u32 hi = (u32)__builtin_amdgcn_readlane(dhi, i);
                    u32 p  = (u32)__builtin_amdgcn_readlane(el, i);
                    u32 q  = (u32)__builtin_amdgcn_readlane(eh, i);
                    alive &= ~(((u64)hi << 32) | (u64)lo);   // on-chain
                    car |= ((u64)q << 32) | (u64)p;          // off-chain
                }
                carry = car;
                if (lane == 0) kbArr[b] = kb;

                // rotate streams (issue b+3)
                d0 = d1; d1 = d2; e0 = e1; e1 = e2;
                if (b + 3 < nblk) {
                    d2 = diagR [((b + 3) << 6) + lane];
                    e2 = carry1[((b + 3) << 6) + lane];
                } else { d2 = 0ULL; e2 = 0ULL; }

                asm volatile("s_waitcnt lgkmcnt(0)" ::: "memory");
                __builtin_amdgcn_s_barrier();
                __builtin_amdgcn_sched_barrier(0);
            }
        } else {
            const int w1 = wave - 1;            // 0..7
            const int chunk = tid & 7;          // row class (rows chunk + 8k)
            const int slot = (tid >> 3) & 7;    // word slot within this wave
            u64 vA[8], vB[8];                   // depth-2 column ring (static indices)

// issue loads feeding the fold at iteration T (block T-1's rows, word W(T)):
#define ISSUE(DST, T)                                                          \
    do {                                                                       \
        const int W_ = (T) + 1 + (w1 << 3) + slot;                             \
        const int Wc_ = (W_ < 64) ? W_ : 63;                                   \
        const u64* cb_ = maskT + ((size_t)Wc_ << 12) + ((size_t)((T) - 1) << 6); \
        _Pragma("unroll")                                                      \
        for (int k = 0; k < 8; ++k) (DST)[k] = cb_[chunk + (k << 3)];          \
    } while (0)

// fold block T-1 into remvArr[W(T)] using ring buffer V:
#define FOLD(V, T)                                                             \
    do {                                                                       \
        const u64 kb_ = kbArr[(T) - 1];                                        \
        const int W_ = (T) + 1 + (w1 << 3) + slot;                             \
        if (W_ < 64 && kb_ != 0ULL) {                                          \
            u64 acc_ = 0ULL;                                                   \
            _Pragma("unroll")                                                  \
            for (int k = 0; k < 8; ++k)                                        \
                acc_ |= (((kb_ >> (chunk + (k << 3))) & 1ULL) ? (V)[k] : 0ULL); \
            acc_ |= __shfl_xor(acc_, 1);                                       \
            acc_ |= __shfl_xor(acc_, 2);                                       \
            acc_ |= __shfl_xor(acc_, 4);                                       \
            if (chunk == 0) remvArr[W_] |= acc_;                               \
        }                                                                      \
    } while (0)

            if (1 < nblk) ISSUE(vA, 1);         // prologue: feed fold@1
            for (int bb = 0; bb < nblk; bb += 2) {
                {   // t = bb (even): fold uses vB
                    if (bb >= 2) FOLD(vB, bb);
                    if (bb + 2 < nblk) ISSUE(vB, bb + 2);
                    asm volatile("s_waitcnt lgkmcnt(0)" ::: "memory");
                    __builtin_amdgcn_s_barrier();
                    __builtin_amdgcn_sched_barrier(0);
                }
                if (bb + 1 < nblk) {  // t = bb+1 (odd): fold uses vA
                    FOLD(vA, bb + 1);
                    if (bb + 3 < nblk) ISSUE(vA, bb + 3);
                    asm volatile("s_waitcnt lgkmcnt(0)" ::: "memory");
                    __builtin_amdgcn_s_barrier();
                    __builtin_amdgcn_sched_barrier(0);
                }
            }
#undef ISSUE
#undef FOLD
        }
    }
    __syncthreads();

    // ---- fused output epilogue ----
    for (int g = tid; g < NBOX * 5; g += 576) {
        const int r = g / 5;
        const int c = g - r * 5;
        bool kept = false;
        if (r < M) kept = ((kbArr[r >> 6] >> (r & 63)) & 1ULL) != 0ULL;
        float vv = 0.0f;
        if (kept) {
            const float* arr = (c == 0) ? sx1 : (c == 1) ? sy1 : (c == 2) ? sx2 : (c == 3) ? sy2 : sconf;
            vv = arr[r];
        }
        out[g] = vv;
    }
}

extern "C" void kernel_launch(void* const* d_in, const int* in_sizes, int n_in,
                              void* d_out, int out_size, void* d_ws, size_t ws_size,
                              hipStream_t stream) {
    const float* raw = (const float*)d_in[0];
    char* ws = (char*)d_ws;
    float* sx1 = (float*)(ws + 0);
    float* sy1 = (float*)(ws + 16384);
    float* sx2 = (float*)(ws + 32768);
    float* sy2 = (float*)(ws + 49152);
    float* sconf = (float*)(ws + 65536);
    int* Mp = (int*)(ws + 81920);
    u64* diagR  = (u64*)(ws + 86016);
    u64* carry1 = (u64*)(ws + 118784);
    u64* maskT = (u64*)(ws + 196608);
    int* rank_partial = (int*)(ws + 2293760);
    float* out = (float*)d_out;

    k_rank<<<dim3(16, 16), dim3(256), 0, stream>>>(raw, rank_partial, Mp);
    k_scatter<<<dim3(16), dim3(256), 0, stream>>>(raw, rank_partial, sx1, sy1, sx2, sy2, sconf, Mp);
    k_mask<<<dim3(16, 64), dim3(256), 0, stream>>>(sx1, sy1, sx2, sy2, Mp, maskT, diagR, carry1);
    k_scan<<<dim3(1), dim3(576), 0, stream>>>(Mp, maskT, diagR, carry1, sx1, sy1, sx2, sy2, sconf, out);
}

// Round 15
// 87.635 us; speedup vs baseline: 1.9014x; 1.0308x over previous
//
#include <hip/hip_runtime.h>
#include <stdint.h>

#define NBOX 4096
#define IMG 640.0f

typedef unsigned long long u64;
typedef unsigned int u32;

// ws layout (bytes):
//   [0      .. 16384)    sx1   (4096 f32, sorted)
//   [16384  .. 32768)    sy1
//   [32768  .. 49152)    sx2
//   [49152  .. 65536)    sy2
//   [65536  .. 81920)    sconf
//   [81920  .. 81924)    M (int)
//   [86016  .. 118784)   diagR  (4096 u64): row r's suppression word blk(r)
//   [118784 .. 151552)   carry1 (4096 u64): row r's suppression word blk(r)+1
//   [196608 .. 2293760)  maskT (COLUMN-major: maskT[word][row], 64 x 4096 u64 = 2 MB)
//   [2293760 .. 2555904) rank_partial (16 x 4096 int = 256 KB)

__global__ __launch_bounds__(256) void k_rank(const float* __restrict__ raw,
                                              int* __restrict__ rank_partial, int* __restrict__ Mp) {
    const int bi = blockIdx.x, bj = blockIdx.y;
    const int t = threadIdx.x;
    const int i = bi * 256 + t;
    if (bi == 0 && bj == 0 && t == 0) *Mp = 0;
    __shared__ float cj[256];
    cj[t] = raw[(bj * 256 + t) * 5 + 4];
    __syncthreads();

    const float ci = raw[i * 5 + 4];
    const int jbase = bj * 256;
    int rank = 0;
    const float4* c4 = reinterpret_cast<const float4*>(cj);
#pragma unroll 4
    for (int j4 = 0; j4 < 64; ++j4) {
        float4 c = c4[j4];
        int j = jbase + j4 * 4;
        rank += (c.x > ci || (c.x == ci && (j + 0) < i)) ? 1 : 0;
        rank += (c.y > ci || (c.y == ci && (j + 1) < i)) ? 1 : 0;
        rank += (c.z > ci || (c.z == ci && (j + 2) < i)) ? 1 : 0;
        rank += (c.w > ci || (c.w == ci && (j + 3) < i)) ? 1 : 0;
    }
    rank_partial[bj * NBOX + i] = rank;
}

__global__ __launch_bounds__(256) void k_scatter(const float* __restrict__ raw,
                                                 const int* __restrict__ rank_partial,
                                                 float* __restrict__ sx1, float* __restrict__ sy1,
                                                 float* __restrict__ sx2, float* __restrict__ sy2,
                                                 float* __restrict__ sconf, int* __restrict__ Mp) {
    const int i = blockIdx.x * 256 + threadIdx.x;
    const float ci = raw[i * 5 + 4];
    const bool vi = (ci >= 0.5f);

    int rank = 0;
#pragma unroll
    for (int k = 0; k < 16; ++k) rank += rank_partial[k * NBOX + i];

    u64 bal = __ballot(vi);
    if ((threadIdx.x & 63) == 0) atomicAdd(Mp, (int)__popcll(bal));

    if (vi) {
        // Strict IEEE ops (no FMA contraction) to match the numpy-evaluated reference.
        float cx = __fmul_rn(raw[i * 5 + 0], IMG);
        float cy = __fmul_rn(raw[i * 5 + 1], IMG);
        float w  = __fmul_rn(raw[i * 5 + 2], IMG);
        float h  = __fmul_rn(raw[i * 5 + 3], IMG);
        float hw = __fmul_rn(w, 0.5f);
        float hh = __fmul_rn(h, 0.5f);
        sx1[rank]   = __fsub_rn(cx, hw);
        sy1[rank]   = __fsub_rn(cy, hh);
        sx2[rank]   = __fadd_rn(cx, hw);
        sy2[rank]   = __fadd_rn(cy, hh);
        sconf[rank] = ci;
    }
}

// Block (bx, w): rows r = bx*256+tid, word w. Column-major store (coalesced);
// also extracts diag word + carry1 column as contiguous arrays.
__global__ __launch_bounds__(256) void k_mask(const float* __restrict__ sx1, const float* __restrict__ sy1,
                                              const float* __restrict__ sx2, const float* __restrict__ sy2,
                                              const int* __restrict__ Mp,
                                              u64* __restrict__ maskT, u64* __restrict__ diagR,
                                              u64* __restrict__ carry1) {
    const int w = blockIdx.y;
    const int r = blockIdx.x * 256 + threadIdx.x;
    const int t = threadIdx.x;
    const int M = *Mp;

    __shared__ float cx1[64], cy1[64], cx2[64], cy2[64], car[64];
    if (t < 64) {
        int j = (w << 6) + t;
        float a1 = sx1[j], b1 = sy1[j], a2 = sx2[j], b2 = sy2[j];
        cx1[t] = a1; cy1[t] = b1; cx2[t] = a2; cy2[t] = b2;
        car[t] = __fmul_rn(__fsub_rn(a2, a1), __fsub_rn(b2, b1));
    }
    __syncthreads();

    u64 bits = 0ULL;
    if (r < M) {
        const float x1 = sx1[r], y1 = sy1[r], x2 = sx2[r], y2 = sy2[r];
        const float area_i = __fmul_rn(__fsub_rn(x2, x1), __fsub_rn(y2, y1));
        const int bmax = min(64, M - (w << 6));       // j < M
        const int bmin = max(0, r + 1 - (w << 6));    // j > r
        for (int b = bmin; b < bmax; ++b) {
            float xx1 = fmaxf(x1, cx1[b]);
            float yy1 = fmaxf(y1, cy1[b]);
            float xx2 = fminf(x2, cx2[b]);
            float yy2 = fminf(y2, cy2[b]);
            float iw = fmaxf(__fsub_rn(xx2, xx1), 0.0f);
            float ih = fmaxf(__fsub_rn(yy2, yy1), 0.0f);
            float inter = __fmul_rn(iw, ih);
            float uni = __fsub_rn(__fadd_rn(area_i, car[b]), inter);
            float iou = __fdiv_rn(inter, fmaxf(uni, 1e-9f));
            if (iou > 0.5f) bits |= (1ULL << b);
        }
        maskT[((size_t)w << 12) + r] = bits;          // coalesced column-major
    }

    const int rblk = r >> 6;
    if (rblk == w)     diagR[r]  = bits;
    if (rblk + 1 == w) carry1[r] = bits;
}

// 9 waves, 1 KiB LDS, 1 barrier/block. PHASE-UNROLLED prefetch (no register
// rotation copies -> no lag-1 vmcnt waits):
//  wave 0 : 6-phase stream ring (d0..d5/e0..e5) -- loads issued 6 blocks ahead.
//  waves 1-8: 3-phase column ring (vA/vB/vC) -- loads issued 3 blocks ahead,
//           addresses depend only on block index (all unconditional streams).
// NOTE: __builtin_amdgcn_readlane returns *int* -- truncate to u32 before
// widening ((u64)(int) sign-extends: R6/R10 bug).
__global__ __launch_bounds__(576) void k_scan(const int* __restrict__ Mp,
                                              const u64* __restrict__ maskT,
                                              const u64* __restrict__ diagR,
                                              const u64* __restrict__ carry1,
                                              const float* __restrict__ sx1, const float* __restrict__ sy1,
                                              const float* __restrict__ sx2, const float* __restrict__ sy2,
                                              const float* __restrict__ sconf,
                                              float* __restrict__ out) {
    __shared__ u64 remvArr[64];
    __shared__ u64 kbArr[64];
    const int tid = threadIdx.x;
    const int wave = tid >> 6;
    const int lane = tid & 63;
    const int M = *Mp;
    const int nblk = (M + 63) >> 6;

    if (tid < 64) { remvArr[tid] = 0ULL; kbArr[tid] = 0ULL; }
    __syncthreads();

    if (nblk > 0) {
        if (wave == 0) {
            __builtin_amdgcn_s_setprio(1);
            u64 d0 = 0, d1 = 0, d2 = 0, d3 = 0, d4 = 0, d5 = 0;
            u64 e0 = 0, e1 = 0, e2 = 0, e3 = 0, e4 = 0, e5 = 0;
            d0 = diagR[lane];                 e0 = carry1[lane];
            if (1 < nblk) { d1 = diagR[(1 << 6) + lane]; e1 = carry1[(1 << 6) + lane]; }
            if (2 < nblk) { d2 = diagR[(2 << 6) + lane]; e2 = carry1[(2 << 6) + lane]; }
            if (3 < nblk) { d3 = diagR[(3 << 6) + lane]; e3 = carry1[(3 << 6) + lane]; }
            if (4 < nblk) { d4 = diagR[(4 << 6) + lane]; e4 = carry1[(4 << 6) + lane]; }
            if (5 < nblk) { d5 = diagR[(5 << 6) + lane]; e5 = carry1[(5 << 6) + lane]; }
            u64 carry = 0ULL;                 // block b-1 kept -> word b

#define W0STEP(B, DD, EE)                                                     \
    do {                                                                      \
        const int b_ = (B);                                                   \
        if (b_ < nblk) {                                                      \
            const u64 rb = remvArr[b_] | carry;                               \
            const int rem = M - (b_ << 6);                                    \
            const u64 valid = (rem >= 64) ? ~0ULL : ((1ULL << rem) - 1ULL);   \
            u64 alive = valid & ~rb;                                          \
            u64 kb = 0ULL, car = 0ULL;                                        \
            const u32 dlo = (u32)(DD), dhi = (u32)((DD) >> 32);               \
            const u32 el = (u32)(EE), eh = (u32)((EE) >> 32);                 \
            while (alive) {                                                   \
                int i = __builtin_ctzll(alive); alive &= alive - 1;           \
                kb |= (1ULL << i);                                            \
                u32 lo = (u32)__builtin_amdgcn_readlane(dlo, i);              \
                u32 hi = (u32)__builtin_amdgcn_readlane(dhi, i);              \
                u32 p  = (u32)__builtin_amdgcn_readlane(el, i);               \
                u32 q  = (u32)__builtin_amdgcn_readlane(eh, i);               \
                alive &= ~(((u64)hi << 32) | (u64)lo);   /* on-chain */       \
                car |= ((u64)q << 32) | (u64)p;          /* off-chain */      \
            }                                                                 \
            carry = car;                                                      \
            if (lane == 0) kbArr[b_] = kb;                                    \
            if (b_ + 6 < nblk) {                                              \
                (DD) = diagR [((b_ + 6) << 6) + lane];                        \
                (EE) = carry1[((b_ + 6) << 6) + lane];                        \
            }                                                                 \
            asm volatile("s_waitcnt lgkmcnt(0)" ::: "memory");                \
            __builtin_amdgcn_s_barrier();                                     \
            __builtin_amdgcn_sched_barrier(0);                                \
        }                                                                     \
    } while (0)

            for (int base = 0; base < nblk; base += 6) {
                W0STEP(base + 0, d0, e0);
                W0STEP(base + 1, d1, e1);
                W0STEP(base + 2, d2, e2);
                W0STEP(base + 3, d3, e3);
                W0STEP(base + 4, d4, e4);
                W0STEP(base + 5, d5, e5);
            }
#undef W0STEP
        } else {
            const int w1 = wave - 1;            // 0..7
            const int chunk = tid & 7;          // row class (rows chunk + 8k)
            const int slot = (tid >> 3) & 7;    // word slot within this wave
            u64 vA[8], vB[8], vC[8];            // 3-phase ring (static indices)

// load buffer V with rows of block T-1, word W(T) (feeds BFOLD(V, T)):
#define BISSUE(V, T)                                                           \
    do {                                                                       \
        const int W_ = (T) + 1 + (w1 << 3) + slot;                             \
        const int Wc_ = (W_ < 64) ? W_ : 63;                                   \
        const u64* cb_ = maskT + ((size_t)Wc_ << 12) + ((size_t)((T) - 1) << 6); \
        _Pragma("unroll")                                                      \
        for (int k = 0; k < 8; ++k) (V)[k] = cb_[chunk + (k << 3)];            \
    } while (0)

// fold block T-1 into remvArr[W(T)]:
#define BFOLD(V, T)                                                            \
    do {                                                                       \
        const u64 kb_ = kbArr[(T) - 1];                                        \
        const int W_ = (T) + 1 + (w1 << 3) + slot;                             \
        if (W_ < 64 && kb_ != 0ULL) {                                          \
            u64 acc_ = 0ULL;                                                   \
            _Pragma("unroll")                                                  \
            for (int k = 0; k < 8; ++k)                                        \
                acc_ |= (((kb_ >> (chunk + (k << 3))) & 1ULL) ? (V)[k] : 0ULL); \
            acc_ |= __shfl_xor(acc_, 1);                                       \
            acc_ |= __shfl_xor(acc_, 2);                                       \
            acc_ |= __shfl_xor(acc_, 4);                                       \
            if (chunk == 0) remvArr[W_] |= acc_;                               \
        }                                                                      \
    } while (0)

#define BSTEP(T, V)                                                            \
    do {                                                                       \
        const int t_ = (T);                                                    \
        if (t_ < nblk) {                                                       \
            if (t_ >= 1) BFOLD(V, t_);                                         \
            if (t_ + 3 < nblk) BISSUE(V, t_ + 3);                              \
            asm volatile("s_waitcnt lgkmcnt(0)" ::: "memory");                 \
            __builtin_amdgcn_s_barrier();                                      \
            __builtin_amdgcn_sched_barrier(0);                                 \
        }                                                                      \
    } while (0)

            if (1 < nblk) BISSUE(vB, 1);     // fold@1 uses vB (1 mod 3)
            if (2 < nblk) BISSUE(vC, 2);     // fold@2 uses vC (2 mod 3)
            for (int base = 0; base < nblk; base += 3) {
                BSTEP(base + 0, vA);
                BSTEP(base + 1, vB);
                BSTEP(base + 2, vC);
            }
#undef BISSUE
#undef BFOLD
#undef BSTEP
        }
    }
    __syncthreads();

    // ---- fused output epilogue ----
    for (int g = tid; g < NBOX * 5; g += 576) {
        const int r = g / 5;
        const int c = g - r * 5;
        bool kept = false;
        if (r < M) kept = ((kbArr[r >> 6] >> (r & 63)) & 1ULL) != 0ULL;
        float vv = 0.0f;
        if (kept) {
            const float* arr = (c == 0) ? sx1 : (c == 1) ? sy1 : (c == 2) ? sx2 : (c == 3) ? sy2 : sconf;
            vv = arr[r];
        }
        out[g] = vv;
    }
}

extern "C" void kernel_launch(void* const* d_in, const int* in_sizes, int n_in,
                              void* d_out, int out_size, void* d_ws, size_t ws_size,
                              hipStream_t stream) {
    const float* raw = (const float*)d_in[0];
    char* ws = (char*)d_ws;
    float* sx1 = (float*)(ws + 0);
    float* sy1 = (float*)(ws + 16384);
    float* sx2 = (float*)(ws + 32768);
    float* sy2 = (float*)(ws + 49152);
    float* sconf = (float*)(ws + 65536);
    int* Mp = (int*)(ws + 81920);
    u64* diagR  = (u64*)(ws + 86016);
    u64* carry1 = (u64*)(ws + 118784);
    u64* maskT = (u64*)(ws + 196608);
    int* rank_partial = (int*)(ws + 2293760);
    float* out = (float*)d_out;

    k_rank<<<dim3(16, 16), dim3(256), 0, stream>>>(raw, rank_partial, Mp);
    k_scatter<<<dim3(16), dim3(256), 0, stream>>>(raw, rank_partial, sx1, sy1, sx2, sy2, sconf, Mp);
    k_mask<<<dim3(16, 64), dim3(256), 0, stream>>>(sx1, sy1, sx2, sy2, Mp, maskT, diagR, carry1);
    k_scan<<<dim3(1), dim3(576), 0, stream>>>(Mp, maskT, diagR, carry1, sx1, sy1, sx2, sy2, sconf, out);
}